// Round 1
// baseline (1135.718 us; speedup 1.0000x reference)
//
#include <hip/hip_runtime.h>

// Problem constants (from reference)
#define NVOLS 24
#define NPTS  32768
#define NIND  18
#define NFEAT 42
#define RES   16
#define HID   32
#define DIN   126   // NFEAT*3
#define NOUTC 144

#define TPB   256
#define NPT   2                       // points per thread
#define PTS_PER_BLOCK (TPB * NPT)     // 512
#define BLOCKS_PER_VOL (NPTS / PTS_PER_BLOCK)  // 64

__global__ __launch_bounds__(TPB, 4) void fused_gridsample_mlp(
    const float* __restrict__ pts,      // (J, P, 3)
    const float* __restrict__ feature,  // (J, F, R, 3)
    const float* __restrict__ ind,      // (J, P, 18)
    const float* __restrict__ w1,       // (J, 126, 32)
    const float* __restrict__ b1,       // (J, 32)
    const float* __restrict__ w2,       // (J, 32, 126)
    const float* __restrict__ b2,       // (J, 126)
    float* __restrict__ out)            // (J, P, 144)
{
    // LDS feature lines, layout [c][f][r] so per-(c,f) reads hit <=15
    // consecutive words -> conflict-free (dup x0 broadcasts).
    __shared__ float sfeat[3 * NFEAT * RES];

    const int j     = blockIdx.x / BLOCKS_PER_VOL;         // volume (uniform)
    const int pbase = (blockIdx.x % BLOCKS_PER_VOL) * PTS_PER_BLOCK;

    // ---- stage feature[j] -> LDS with (f,r,c) -> [c][f][r] transpose ----
    const float* fj = feature + j * (NFEAT * RES * 3);
    for (int e = threadIdx.x; e < NFEAT * RES * 3; e += TPB) {
        int f   = e / (RES * 3);
        int rem = e - f * (RES * 3);
        int r   = rem / 3;
        int c   = rem - r * 3;
        sfeat[(c * NFEAT + f) * RES + r] = fj[e];
    }
    __syncthreads();

    // Block-uniform weight bases (scalar loads expected)
    const float* w1j = w1 + j * (DIN * HID);
    const float* b1j = b1 + j * HID;
    const float* w2j = w2 + j * (HID * DIN);
    const float* b2j = b2 + j * DIN;

    // ---- per-point interp setup ----
    int   p[NPT];
    float wfr[NPT][3];
    int   xbase[NPT][3];   // LDS word index base: c*NFEAT*RES + x0 (add f*RES in loop)
    #pragma unroll
    for (int t = 0; t < NPT; t++) {
        p[t] = pbase + (int)threadIdx.x + t * TPB;
        const float* pp = pts + ((j * NPTS + p[t]) * 3);
        #pragma unroll
        for (int c = 0; c < 3; c++) {
            float x = (pp[c] + 1.0f) * 7.5f;        // (x+1)*0.5*(R-1), single-round equiv
            x = fminf(fmaxf(x, 0.0f), 15.0f);
            int x0 = (int)floorf(x);
            x0 = min(x0, RES - 2);
            wfr[t][c]   = x - (float)x0;
            xbase[t][c] = c * (NFEAT * RES) + x0;
        }
    }

    // ---- layer 1: h = relu(v @ w1 + b1), v streamed from LDS interp ----
    float h[NPT][HID];
    #pragma unroll
    for (int t = 0; t < NPT; t++)
        #pragma unroll
        for (int o = 0; o < HID; o++)
            h[t][o] = b1j[o];

    for (int f = 0; f < NFEAT; f++) {
        #pragma unroll
        for (int c = 0; c < 3; c++) {
            float v[NPT];
            #pragma unroll
            for (int t = 0; t < NPT; t++) {
                int idx  = xbase[t][c] + f * RES;
                float g0 = sfeat[idx];
                float g1 = sfeat[idx + 1];
                v[t] = fmaf(wfr[t][c], g1 - g0, g0);
            }
            const float* wrow = w1j + (f * 3 + c) * HID;  // uniform row
            #pragma unroll
            for (int o = 0; o < HID; o++) {
                float wv = wrow[o];
                #pragma unroll
                for (int t = 0; t < NPT; t++)
                    h[t][o] = fmaf(v[t], wv, h[t][o]);
            }
        }
    }
    #pragma unroll
    for (int t = 0; t < NPT; t++)
        #pragma unroll
        for (int o = 0; o < HID; o++)
            h[t][o] = fmaxf(h[t][o], 0.0f);

    // ---- ind_feature passthrough (18 floats, 8B-aligned) ----
    float* outp[NPT];
    #pragma unroll
    for (int t = 0; t < NPT; t++) {
        outp[t] = out + (size_t)(j * NPTS + p[t]) * NOUTC;
        const float* indp = ind + ((j * NPTS + p[t]) * NIND);
        #pragma unroll
        for (int q = 0; q < NIND / 2; q++) {
            float2 v = ((const float2*)indp)[q];
            ((float2*)outp[t])[q] = v;
        }
    }

    // ---- layer 2: o = h @ w2 + b2, streamed in k-pairs (float2 stores) ----
    #pragma unroll 3
    for (int k = 0; k < DIN; k += 2) {
        float acc[NPT][2];
        float bk0 = b2j[k], bk1 = b2j[k + 1];
        #pragma unroll
        for (int t = 0; t < NPT; t++) { acc[t][0] = bk0; acc[t][1] = bk1; }
        #pragma unroll
        for (int o = 0; o < HID; o++) {
            float w0 = w2j[o * DIN + k];        // uniform
            float w1v = w2j[o * DIN + k + 1];   // uniform
            #pragma unroll
            for (int t = 0; t < NPT; t++) {
                acc[t][0] = fmaf(h[t][o], w0,  acc[t][0]);
                acc[t][1] = fmaf(h[t][o], w1v, acc[t][1]);
            }
        }
        #pragma unroll
        for (int t = 0; t < NPT; t++) {
            *(float2*)(outp[t] + NIND + k) = make_float2(acc[t][0], acc[t][1]);
        }
    }
}

extern "C" void kernel_launch(void* const* d_in, const int* in_sizes, int n_in,
                              void* d_out, int out_size, void* d_ws, size_t ws_size,
                              hipStream_t stream) {
    const float* pts     = (const float*)d_in[0];
    const float* feature = (const float*)d_in[1];
    const float* ind     = (const float*)d_in[2];
    const float* w1      = (const float*)d_in[3];
    const float* b1      = (const float*)d_in[4];
    const float* w2      = (const float*)d_in[5];
    const float* b2      = (const float*)d_in[6];
    float* out           = (float*)d_out;

    dim3 grid(NVOLS * BLOCKS_PER_VOL);   // 24 * 64 = 1536 blocks
    dim3 block(TPB);
    fused_gridsample_mlp<<<grid, block, 0, stream>>>(pts, feature, ind, w1, b1, w2, b2, out);
}

// Round 2
// 799.364 us; speedup vs baseline: 1.4208x; 1.4208x over previous
//
#include <hip/hip_runtime.h>

// Problem constants
#define NVOLS 24
#define NPTS  32768
#define NIND  18
#define NFEAT 42
#define RES   16
#define HID   32
#define DIN   126   // NFEAT*3
#define NOUTC 144

#define TPB   256
#define PPB   256                     // points per block (1 pt/thread)
#define BLOCKS_PER_VOL (NPTS / PPB)   // 128
#define CHUNK 64                      // points per output chunk (one wave owns it)
#define NCHUNK (PPB / CHUNK)          // 4

// LDS regions (floats)
#define SFEAT_N     (3 * NFEAT * RES)     // 2016
#define SHHC_STRIDE 33                    // 64x32 h tile, +1 pad (conflict-free)
#define SHHC_N      (CHUNK * SHHC_STRIDE) // 2112
#define SOUT_STRIDE 127                   // 126 outputs, odd stride (conflict-free)
#define SOUT_N      (CHUNK * SOUT_STRIDE) // 8128
#define SIND_N      (CHUNK * NIND)        // 1152
// total = (2016+2112+8128+1152)*4 = 53,632 B -> 3 blocks/CU

typedef float f4 __attribute__((ext_vector_type(4)));

__global__ __launch_bounds__(TPB, 3) void fused_gridsample_mlp(
    const float* __restrict__ pts,      // (J, P, 3)
    const float* __restrict__ feature,  // (J, F, R, 3)
    const float* __restrict__ ind,      // (J, P, 18)
    const float* __restrict__ w1,       // (J, 126, 32)
    const float* __restrict__ b1,       // (J, 32)
    const float* __restrict__ w2,       // (J, 32, 126)
    const float* __restrict__ b2,       // (J, 126)
    float* __restrict__ out)            // (J, P, 144)
{
    __shared__ float sfeat[SFEAT_N];
    __shared__ float sh_hc[SHHC_N];
    __shared__ float sh_out[SOUT_N];
    __shared__ float sh_ind[SIND_N];

    const int tid   = threadIdx.x;
    const int j     = blockIdx.x / BLOCKS_PER_VOL;
    const int pbase = (blockIdx.x % BLOCKS_PER_VOL) * PPB;

    // ---- stage feature[j] -> LDS as [c][f][r] ----
    const float* fj = feature + j * (NFEAT * RES * 3);
    for (int e = tid; e < SFEAT_N; e += TPB) {
        int f   = e / (RES * 3);
        int rem = e - f * (RES * 3);
        int r   = rem / 3;
        int c   = rem - r * 3;
        sfeat[(c * NFEAT + f) * RES + r] = fj[e];
    }

    // ---- interp setup (1 point per thread) ----
    const int p = pbase + tid;
    float wfr[3]; int xb[3];
    {
        const float* pp = pts + (size_t)(j * NPTS + p) * 3;
        #pragma unroll
        for (int c = 0; c < 3; c++) {
            float x = (pp[c] + 1.0f) * 7.5f;
            x = fminf(fmaxf(x, 0.0f), 15.0f);
            int x0 = (int)x;            // x >= 0 -> trunc == floor
            x0 = min(x0, RES - 2);
            wfr[c] = x - (float)x0;
            xb[c]  = c * (NFEAT * RES) + x0;
        }
    }
    __syncthreads();

    // ---- layer 1: h = relu(v @ w1 + b1), weights via scalar loads ----
    const float* w1j = w1 + j * (DIN * HID);
    const float* b1j = b1 + j * HID;
    float h[HID];
    #pragma unroll
    for (int o = 0; o < HID; o++) h[o] = b1j[o];

    for (int f = 0; f < NFEAT; f++) {
        #pragma unroll
        for (int c = 0; c < 3; c++) {
            int   idx = xb[c] + f * RES;
            float g0  = sfeat[idx];
            float g1  = sfeat[idx + 1];
            float v   = fmaf(wfr[c], g1 - g0, g0);
            const float* wrow = w1j + (f * 3 + c) * HID;  // uniform row
            #pragma unroll
            for (int o = 0; o < HID; o++)
                h[o] = fmaf(v, wrow[o], h[o]);
        }
    }
    #pragma unroll
    for (int o = 0; o < HID; o++) h[o] = fmaxf(h[o], 0.0f);

    // ---- layer 2 + coalesced epilogue, per 64-pt chunk ----
    const float* w2j = w2 + j * (HID * DIN);
    const float* b2j = b2 + j * DIN;
    const int wave = tid >> 6;
    const int psub = tid & 63;
    // wave-uniform k-slice base -> keeps w2/b2 on scalar loads
    const int k0 = __builtin_amdgcn_readfirstlane((tid >> 6) * 32);

    for (int c = 0; c < NCHUNK; c++) {
        // owning wave deposits its h tile (conflict-free: stride 33)
        if (wave == c) {
            #pragma unroll
            for (int o = 0; o < HID; o++)
                sh_hc[psub * SHHC_STRIDE + o] = h[o];
        }
        __syncthreads();

        // ind passthrough: coalesced global float2 -> LDS (flat [64][18])
        const float* indc = ind + (size_t)(j * NPTS + pbase + c * CHUNK) * NIND;
        #pragma unroll
        for (int i2 = 0; i2 < 3; i2++) {
            int f2 = i2 * TPB + tid;
            if (f2 < CHUNK * NIND / 2) {
                float2 v = ((const float2*)indc)[f2];
                sh_ind[f2 * 2]     = v.x;
                sh_ind[f2 * 2 + 1] = v.y;
            }
        }

        // compute my k-slice (32 outputs; wave3 has 30 real ones) for point c*64+psub
        float acc[32];
        #pragma unroll
        for (int kk = 0; kk < 32; kk++) {
            int kc = min(k0 + kk, DIN - 1);   // clamp keeps loads in-bounds & uniform
            acc[kk] = b2j[kc];
        }
        #pragma unroll 4
        for (int o = 0; o < HID; o++) {
            float hho = sh_hc[psub * SHHC_STRIDE + o];
            const float* wrow = w2j + o * DIN;  // uniform
            #pragma unroll
            for (int kk = 0; kk < 32; kk++) {
                int kc = min(k0 + kk, DIN - 1);
                acc[kk] = fmaf(hho, wrow[kc], acc[kk]);
            }
        }
        #pragma unroll
        for (int kk = 0; kk < 32; kk++) {
            int k = k0 + kk;
            if (k < DIN)
                sh_out[psub * SOUT_STRIDE + k] = acc[kk];
        }
        __syncthreads();

        // coalesced, line-dense copy: 64 rows x 144 floats = 2304 float4
        float* outc = out + (size_t)(j * NPTS + pbase + c * CHUNK) * NOUTC;
        #pragma unroll
        for (int i = 0; i < (CHUNK * NOUTC / 4) / TPB; i++) {   // 9 iters
            int flat4 = i * TPB + tid;
            int pr = flat4 / 36;
            int q  = flat4 - pr * 36;
            f4 v;
            if (q < 4) {
                int b = pr * NIND + 4 * q;
                v = (f4){sh_ind[b], sh_ind[b + 1], sh_ind[b + 2], sh_ind[b + 3]};
            } else if (q == 4) {
                int b = pr * NIND + 16;
                int s = pr * SOUT_STRIDE;
                v = (f4){sh_ind[b], sh_ind[b + 1], sh_out[s], sh_out[s + 1]};
            } else {
                int s = pr * SOUT_STRIDE + (4 * q - NIND);
                v = (f4){sh_out[s], sh_out[s + 1], sh_out[s + 2], sh_out[s + 3]};
            }
            __builtin_nontemporal_store(v, (f4*)outc + flat4);
        }
        __syncthreads();   // sh_out/sh_ind reused next chunk
    }
}

extern "C" void kernel_launch(void* const* d_in, const int* in_sizes, int n_in,
                              void* d_out, int out_size, void* d_ws, size_t ws_size,
                              hipStream_t stream) {
    const float* pts     = (const float*)d_in[0];
    const float* feature = (const float*)d_in[1];
    const float* ind     = (const float*)d_in[2];
    const float* w1      = (const float*)d_in[3];
    const float* b1      = (const float*)d_in[4];
    const float* w2      = (const float*)d_in[5];
    const float* b2      = (const float*)d_in[6];
    float* out           = (float*)d_out;

    dim3 grid(NVOLS * BLOCKS_PER_VOL);   // 24 * 128 = 3072 blocks
    dim3 block(TPB);
    fused_gridsample_mlp<<<grid, block, 0, stream>>>(pts, feature, ind, w1, b1, w2, b2, out);
}

// Round 3
// 785.383 us; speedup vs baseline: 1.4461x; 1.0178x over previous
//
#include <hip/hip_runtime.h>

// Problem constants
#define NVOLS 24
#define NPTS  32768
#define NIND  18
#define NFEAT 42
#define RES   16
#define HID   32
#define DIN   126   // NFEAT*3
#define NOUTC 144

#define TPB   256
#define PPB   256                     // points per block (1 pt/thread)
#define BLOCKS_PER_VOL (NPTS / PPB)   // 128
#define CHUNK 64                      // points per output chunk (one wave owns it)
#define NCHUNK (PPB / CHUNK)          // 4

// LDS regions (floats)
#define SFEAT_N     (3 * NFEAT * RES)     // 2016
#define SHHC_STRIDE 33                    // 64x32 h tile, +1 pad (conflict-free)
#define SHHC_N      (CHUNK * SHHC_STRIDE) // 2112
#define SOUT_STRIDE 127                   // odd stride -> conflict-free b32 scatter
#define SOUT_N      (CHUNK * SOUT_STRIDE) // 8128
// total = (2016+2112+8128)*4 = 49,024 B -> 3 blocks/CU

// Layer-2 k-slice with COMPILE-TIME offsets: w2/b2 reads become batched
// s_load_dwordx8 (block-uniform addresses), no per-element clamp/s_min.
template<int K0, int KLEN>
__device__ __forceinline__ void layer2_slice(
    const float* __restrict__ w2j, const float* __restrict__ b2j,
    const float* hrow, float* orow)
{
    float acc[KLEN];
    #pragma unroll
    for (int kk = 0; kk < KLEN; kk++) acc[kk] = b2j[K0 + kk];
    #pragma unroll
    for (int o = 0; o < HID; o++) {
        float hho = hrow[o];                     // ds_read_b32, stride-33 rows
        #pragma unroll
        for (int kk = 0; kk < KLEN; kk++)
            acc[kk] = fmaf(hho, w2j[o * DIN + K0 + kk], acc[kk]);  // SGPR operand
    }
    #pragma unroll
    for (int kk = 0; kk < KLEN; kk++) orow[K0 + kk] = acc[kk];
}

__global__ __launch_bounds__(TPB, 3) void fused_gridsample_mlp(
    const float* __restrict__ pts,      // (J, P, 3)
    const float* __restrict__ feature,  // (J, F, R, 3)
    const float* __restrict__ ind,      // (J, P, 18)
    const float* __restrict__ w1,       // (J, 126, 32)
    const float* __restrict__ b1,       // (J, 32)
    const float* __restrict__ w2,       // (J, 32, 126)
    const float* __restrict__ b2,       // (J, 126)
    float* __restrict__ out)            // (J, P, 144)
{
    __shared__ float sfeat[SFEAT_N];
    __shared__ float sh_hc[SHHC_N];
    __shared__ float sh_out[SOUT_N];

    const int tid   = threadIdx.x;
    const int j     = blockIdx.x / BLOCKS_PER_VOL;
    const int pbase = (blockIdx.x % BLOCKS_PER_VOL) * PPB;

    // ---- stage feature[j] -> LDS as [c][f][r] ----
    const float* fj = feature + j * (NFEAT * RES * 3);
    for (int e = tid; e < SFEAT_N; e += TPB) {
        int f   = e / (RES * 3);
        int rem = e - f * (RES * 3);
        int r   = rem / 3;
        int c   = rem - r * 3;
        sfeat[(c * NFEAT + f) * RES + r] = fj[e];
    }

    // ---- interp setup (1 point per thread) ----
    const int p = pbase + tid;
    float wfr[3]; int xb[3];
    {
        const float* pp = pts + (size_t)(j * NPTS + p) * 3;
        #pragma unroll
        for (int c = 0; c < 3; c++) {
            float x = (pp[c] + 1.0f) * 7.5f;
            x = fminf(fmaxf(x, 0.0f), 15.0f);
            int x0 = (int)x;            // x >= 0 -> trunc == floor
            x0 = min(x0, RES - 2);
            wfr[c] = x - (float)x0;
            xb[c]  = c * (NFEAT * RES) + x0;
        }
    }
    __syncthreads();

    // ---- layer 1: h = relu(v @ w1 + b1), weights via scalar loads ----
    const float* w1j = w1 + j * (DIN * HID);
    const float* b1j = b1 + j * HID;
    float h[HID];
    #pragma unroll
    for (int o = 0; o < HID; o++) h[o] = b1j[o];

    for (int f = 0; f < NFEAT; f++) {
        #pragma unroll
        for (int c = 0; c < 3; c++) {
            int   idx = xb[c] + f * RES;
            float g0  = sfeat[idx];
            float g1  = sfeat[idx + 1];
            float v   = fmaf(wfr[c], g1 - g0, g0);
            const float* wrow = w1j + (f * 3 + c) * HID;  // uniform row
            #pragma unroll
            for (int o = 0; o < HID; o++)
                h[o] = fmaf(v, wrow[o], h[o]);
        }
    }
    #pragma unroll
    for (int o = 0; o < HID; o++) h[o] = fmaxf(h[o], 0.0f);

    // ---- layer 2 + coalesced epilogue, per 64-pt chunk ----
    const float* w2j = w2 + j * (HID * DIN);
    const float* b2j = b2 + j * DIN;
    const int wave = tid >> 6;
    const int psub = tid & 63;
    const int wv = __builtin_amdgcn_readfirstlane(wave);  // force uniform branch

    for (int c = 0; c < NCHUNK; c++) {
        // owning wave deposits its h tile (stride 33: conflict-free)
        if (wave == c) {
            #pragma unroll
            for (int o = 0; o < HID; o++)
                sh_hc[psub * SHHC_STRIDE + o] = h[o];
        }
        __syncthreads();   // sh_hc ready; also guards sh_out reuse vs prev pass B

        // layer-2 k-slice (compile-time offsets per wave)
        {
            const float* hrow = sh_hc + psub * SHHC_STRIDE;
            float* orow = sh_out + psub * SOUT_STRIDE;
            if      (wv == 0) layer2_slice< 0, 32>(w2j, b2j, hrow, orow);
            else if (wv == 1) layer2_slice<32, 32>(w2j, b2j, hrow, orow);
            else if (wv == 2) layer2_slice<64, 32>(w2j, b2j, hrow, orow);
            else              layer2_slice<96, 30>(w2j, b2j, hrow, orow);
        }

        // pass A: ind passthrough, global->global f2 copy (coalesced both sides)
        {
            const float* indc = ind + (size_t)(j * NPTS + pbase + c * CHUNK) * NIND;
            float* outc = out + (size_t)(j * NPTS + pbase + c * CHUNK) * NOUTC;
            #pragma unroll
            for (int i = 0; i < 3; i++) {            // 576 f2 units / 256 threads
                int u = i * TPB + tid;
                if (u < CHUNK * NIND / 2) {
                    float2 v = ((const float2*)indc)[u];
                    int pr = u / 9;
                    int m  = u - pr * 9;
                    *(float2*)(outc + pr * NOUTC + 2 * m) = v;
                }
            }
        }
        __syncthreads();   // sh_out ready

        // pass B: sh_out -> out cols 18..143, f2 units (stride-2 b32 reads: free)
        {
            float* outc = out + (size_t)(j * NPTS + pbase + c * CHUNK) * NOUTC;
            #pragma unroll 4
            for (int i = 0; i < 16; i++) {           // 4032 f2 units / 256 threads
                int u = i * TPB + tid;
                if (u < CHUNK * (DIN / 2)) {
                    int pr = u / 63;
                    int m  = u - pr * 63;
                    float a0 = sh_out[pr * SOUT_STRIDE + 2 * m];
                    float a1 = sh_out[pr * SOUT_STRIDE + 2 * m + 1];
                    *(float2*)(outc + pr * NOUTC + NIND + 2 * m) = make_float2(a0, a1);
                }
            }
        }
        // next chunk's first __syncthreads guards sh_out rewrite
    }
}

extern "C" void kernel_launch(void* const* d_in, const int* in_sizes, int n_in,
                              void* d_out, int out_size, void* d_ws, size_t ws_size,
                              hipStream_t stream) {
    const float* pts     = (const float*)d_in[0];
    const float* feature = (const float*)d_in[1];
    const float* ind     = (const float*)d_in[2];
    const float* w1      = (const float*)d_in[3];
    const float* b1      = (const float*)d_in[4];
    const float* w2      = (const float*)d_in[5];
    const float* b2      = (const float*)d_in[6];
    float* out           = (float*)d_out;

    dim3 grid(NVOLS * BLOCKS_PER_VOL);   // 24 * 128 = 3072 blocks
    dim3 block(TPB);
    fused_gridsample_mlp<<<grid, block, 0, stream>>>(pts, feature, ind, w1, b1, w2, b2, out);
}